// Round 5
// baseline (1450.768 us; speedup 1.0000x reference)
//
#include <hip/hip_runtime.h>

// ---------------------------------------------------------------------------
// LSTMGRUHybrid: B=512, T=512, D=128, H=128 (4H=512), G=128 (3G=384), F=160, C=64
// Round 5: input projections fused INTO the scans (x-proj MFMA for step t+1
// runs during step t, double-buffered acc; x-frags prefetched 2 steps ahead).
// Both standalone GEMMs and the gx buffer are gone. LDS h stride 136->140
// (writes cover all 32 banks). Pipeline: prep_x, prep_misc, lstm_scan,
// ln_pass, gru_scan, head.
// ---------------------------------------------------------------------------

typedef __attribute__((ext_vector_type(8))) short bf16x8;
typedef __attribute__((ext_vector_type(4))) float f32x4;
typedef __attribute__((ext_vector_type(4))) int i32x4;
typedef unsigned short u16;
typedef unsigned int u32;

#define BT 262144          // B*T
#define TT 512
#define HSTR 140           // hbuf row stride in u16 (byte 280 = 24 mod 128)

__device__ __forceinline__ u16 f2bf(float f) {
  u32 u = __builtin_bit_cast(u32, f);
  u += 0x7fffu + ((u >> 16) & 1u);
  return (u16)(u >> 16);
}
__device__ __forceinline__ float bf2f(u16 h) {
  return __builtin_bit_cast(float, (u32)h << 16);
}
__device__ __forceinline__ u32 packbf2(float a, float b) {
  return (u32)f2bf(a) | ((u32)f2bf(b) << 16);
}
__device__ __forceinline__ bf16x8 ldg8(const u16* p) {
  return __builtin_bit_cast(bf16x8, *(const i32x4*)p);
}
// fast sigmoid/tanh: v_rcp instead of IEEE div sequence
__device__ __forceinline__ float frcp(float x) { return __builtin_amdgcn_rcpf(x); }
__device__ __forceinline__ float sigm(float x) { return frcp(1.f + __expf(-x)); }
__device__ __forceinline__ float tanh_f(float x) {
  return 1.f - 2.f * frcp(__expf(2.f * x) + 1.f);
}
// barrier draining LDS only (vmcnt stays outstanding: x prefetch + lout stores
// remain off the per-step critical path). 0xC07F = vmcnt(63) expcnt(7) lgkm(0)
__device__ __forceinline__ void scan_barrier() {
  __asm__ volatile("" ::: "memory");
  __builtin_amdgcn_s_waitcnt(0xC07F);
  __builtin_amdgcn_s_barrier();
  __asm__ volatile("" ::: "memory");
}

// ---------------------------------------------------------------------------
// prep kernels
// ---------------------------------------------------------------------------
__global__ void prep_x(const float* __restrict__ x, u16* __restrict__ xb) {
  size_t i = ((size_t)blockIdx.x * 256 + threadIdx.x) * 4;
  float4 v = *(const float4*)(x + i);
  *(uint2*)(xb + i) = make_uint2(packbf2(v.x, v.y), packbf2(v.z, v.w));
}

__global__ void prep_misc(
    const float* __restrict__ wihl, const float* __restrict__ whhl,
    const float* __restrict__ wihg, const float* __restrict__ whhg,
    const float* __restrict__ bihl, const float* __restrict__ bhhl,
    const float* __restrict__ fc1W, const float* __restrict__ fcoW,
    u16* __restrict__ wihlb, u16* __restrict__ whhlb,
    u16* __restrict__ wihgb, u16* __restrict__ whhgb,
    float* __restrict__ biasl, float* __restrict__ fc1Wt, float* __restrict__ fcoWt) {
  int i = blockIdx.x * 256 + threadIdx.x;
  if (i < 65536) {
    wihlb[i] = f2bf(wihl[i]);
  } else if (i < 131072) {
    int k = i - 65536; whhlb[k] = f2bf(whhl[k]);
  } else if (i < 180224) {
    int k = i - 131072; wihgb[k] = f2bf(wihg[k]);
  } else if (i < 229376) {
    int k = i - 180224; whhgb[k] = f2bf(whhg[k]);
  } else if (i < 229888) {
    int k = i - 229376; biasl[k] = bihl[k] + bhhl[k];
  } else if (i < 250368) {
    int k = i - 229888;                       // fc1Wt[g*160+f] = fc1W[f*128+g]
    fc1Wt[k] = fc1W[(k % 160) * 128 + (k / 160)];
  } else if (i < 260608) {
    int k = i - 250368;                       // fcoWt[f*64+c] = fcoW[c*160+f]
    fcoWt[k] = fcoW[(k % 64) * 160 + (k / 64)];
  }
}

// ---------------------------------------------------------------------------
// LSTM scan + fused x-projection. 128 blocks x 512 thr; 4 batch rows/block at
// MFMA rows {0,4,8,12} (each lane owns one gate element, C reg 0). Wave w owns
// hidden cols [w*16,w*16+16); N-tiles = 4 gates. x-proj for t+1 MFMA'd during
// step t (frags prefetched 2 steps ahead, accumulator double-buffered).
// ---------------------------------------------------------------------------
__global__ __launch_bounds__(512) void lstm_scan(
    const u16* __restrict__ xb,    // [B][T][128] bf16
    const u16* __restrict__ whh,   // [512][128] bf16
    const u16* __restrict__ wih,   // [512][128] bf16
    const float* __restrict__ biasl, // [512] = bih+bhh
    u16* __restrict__ lout) {      // [B][T][128] bf16 raw h
  const int tid = threadIdx.x;
  const int w = tid >> 6, l = tid & 63;
  const int hc = l & 15, q = l >> 4;
  const int col = w * 16 + hc;
  const int b0 = blockIdx.x * 4;
  const int mrow = q * 4;
  __shared__ __align__(16) u16 hb0[16 * HSTR];
  __shared__ __align__(16) u16 hb1[16 * HSTR];

  bf16x8 wfh[4][4], wfx[4][4];
#pragma unroll
  for (int g = 0; g < 4; g++)
#pragma unroll
    for (int k0 = 0; k0 < 4; k0++) {
      wfh[g][k0] = ldg8(&whh[(g * 128 + col) * 128 + k0 * 32 + q * 8]);
      wfx[g][k0] = ldg8(&wih[(g * 128 + col) * 128 + k0 * 32 + q * 8]);
    }
  float bsl[4];
#pragma unroll
  for (int g = 0; g < 4; g++) bsl[g] = biasl[g * 128 + col];

  float c = 0.f;
  // A-side x fragment source: batch row b0+(hc>>2) (all lanes load; MFMA rows
  // are independent so redundant/garbage rows never touch valid C rows)
  const u32 xrow = (u32)(b0 + (hc >> 2)) * (TT * 128) + q * 8;
  u32 loff = (u32)(b0 + q) * (TT * 128) + col;
  const int hbase = hc * HSTR + q * 8;
  for (int i = tid; i < 16 * HSTR; i += 512) { hb0[i] = 0; hb1[i] = 0; }

  // prologue: axa = x-proj(t=0); fa = frags(t=1)
  bf16x8 fa[4], fb[4];
  f32x4 axa[4], axb[4];
  {
    bf16x8 f0[4];
#pragma unroll
    for (int k0 = 0; k0 < 4; k0++) {
      f0[k0] = ldg8(&xb[xrow + 0 * 128 + k0 * 32]);
      fa[k0] = ldg8(&xb[xrow + 1 * 128 + k0 * 32]);
    }
#pragma unroll
    for (int g = 0; g < 4; g++) axa[g] = (f32x4){0.f, 0.f, 0.f, 0.f};
#pragma unroll
    for (int k0 = 0; k0 < 4; k0++)
#pragma unroll
      for (int g = 0; g < 4; g++)
        axa[g] = __builtin_amdgcn_mfma_f32_16x16x32_bf16(f0[k0], wfx[g][k0], axa[g], 0, 0, 0);
  }
  scan_barrier();

  auto step = [&](int t, bf16x8 (&fcur)[4], bf16x8 (&fnext)[4],
                  f32x4 (&axc)[4], f32x4 (&axn)[4], const u16* hrd, u16* hwr) {
    // prefetch x frags for t+2 (used for x-MFMA next step)
#pragma unroll
    for (int k0 = 0; k0 < 4; k0++)
      fnext[k0] = ldg8(&xb[xrow + (u32)(t + 2) * 128 + k0 * 32]);
    // h(t-1) @ Whh^T
    bf16x8 af[4];
#pragma unroll
    for (int k0 = 0; k0 < 4; k0++) af[k0] = ldg8(&hrd[hbase + k0 * 32]);
    f32x4 ah[4];
#pragma unroll
    for (int g = 0; g < 4; g++) ah[g] = (f32x4){0.f, 0.f, 0.f, 0.f};
#pragma unroll
    for (int k0 = 0; k0 < 4; k0++)
#pragma unroll
      for (int g = 0; g < 4; g++)
        ah[g] = __builtin_amdgcn_mfma_f32_16x16x32_bf16(af[k0], wfh[g][k0], ah[g], 0, 0, 0);
    // x-proj for t+1 (independent of recurrence -> fills stall cycles)
#pragma unroll
    for (int g = 0; g < 4; g++) axn[g] = (f32x4){0.f, 0.f, 0.f, 0.f};
#pragma unroll
    for (int k0 = 0; k0 < 4; k0++)
#pragma unroll
      for (int g = 0; g < 4; g++)
        axn[g] = __builtin_amdgcn_mfma_f32_16x16x32_bf16(fcur[k0], wfx[g][k0], axn[g], 0, 0, 0);
    // gates (single element per lane: C reg 0 = batch b0+q, hidden col)
    float pi = ah[0][0] + axc[0][0] + bsl[0];
    float pf = ah[1][0] + axc[1][0] + bsl[1];
    float pg = ah[2][0] + axc[2][0] + bsl[2];
    float po = ah[3][0] + axc[3][0] + bsl[3];
    c = sigm(pf) * c + sigm(pi) * tanh_f(pg);
    float h = sigm(po) * tanh_f(c);
    u16 hv = f2bf(h);
    hwr[mrow * HSTR + col] = hv;
    lout[loff] = hv;
    loff += 128;
    scan_barrier();
  };

#pragma unroll 1
  for (int t2 = 0; t2 < TT; t2 += 2) {
    step(t2, fa, fb, axa, axb, hb0, hb1);
    step(t2 + 1, fb, fa, axb, axa, hb1, hb0);
  }
}

// ---------------------------------------------------------------------------
// In-place row LayerNorm over [BT][128] bf16. One wave per row.
// ---------------------------------------------------------------------------
__global__ __launch_bounds__(256) void ln_pass(
    u16* __restrict__ buf, const float* __restrict__ g, const float* __restrict__ b) {
  const size_t row = (size_t)blockIdx.x * 4 + (threadIdx.x >> 6);
  const int l = threadIdx.x & 63;
  u16* p = buf + row * 128 + l * 2;
  u32 v = *(const u32*)p;
  float a0 = bf2f((u16)v), a1 = bf2f((u16)(v >> 16));
  float s1 = a0 + a1, s2 = a0 * a0 + a1 * a1;
#pragma unroll
  for (int m = 1; m < 64; m <<= 1) { s1 += __shfl_xor(s1, m); s2 += __shfl_xor(s2, m); }
  float mean = s1 * 0.0078125f;
  float var = s2 * 0.0078125f - mean * mean;
  float rs = rsqrtf(var + 1e-5f);
  float2 gg = *(const float2*)(g + l * 2);
  float2 bb = *(const float2*)(b + l * 2);
  float y0 = (a0 - mean) * rs * gg.x + bb.x;
  float y1 = (a1 - mean) * rs * gg.y + bb.y;
  *(u32*)p = packbf2(y0, y1);
}

// ---------------------------------------------------------------------------
// GRU scan + fused x-projection (x = LayerNormed lout). 128 blocks x 4 rows.
// ---------------------------------------------------------------------------
__global__ __launch_bounds__(512) void gru_scan(
    const u16* __restrict__ xb,    // [B][T][128] bf16 (LN'd lstm out)
    const u16* __restrict__ whh,   // [384][128] bf16
    const u16* __restrict__ wih,   // [384][128] bf16
    const float* __restrict__ bih, const float* __restrict__ bhh,
    float* __restrict__ hlast) {   // [512][128] fp32
  const int tid = threadIdx.x;
  const int w = tid >> 6, l = tid & 63;
  const int hc = l & 15, q = l >> 4;
  const int col = w * 16 + hc;
  const int b0 = blockIdx.x * 4;
  const int mrow = q * 4;
  __shared__ __align__(16) u16 hb0[16 * HSTR];
  __shared__ __align__(16) u16 hb1[16 * HSTR];

  bf16x8 wfh[3][4], wfx[3][4];
#pragma unroll
  for (int g = 0; g < 3; g++)
#pragma unroll
    for (int k0 = 0; k0 < 4; k0++) {
      wfh[g][k0] = ldg8(&whh[(g * 128 + col) * 128 + k0 * 32 + q * 8]);
      wfx[g][k0] = ldg8(&wih[(g * 128 + col) * 128 + k0 * 32 + q * 8]);
    }
  const float brz = bih[col] + bhh[col];
  const float bzz = bih[128 + col] + bhh[128 + col];
  const float bnx = bih[256 + col], bnh = bhh[256 + col];

  float hp = 0.f;
  const u32 xrow = (u32)(b0 + (hc >> 2)) * (TT * 128) + q * 8;
  const int hbase = hc * HSTR + q * 8;
  for (int i = tid; i < 16 * HSTR; i += 512) { hb0[i] = 0; hb1[i] = 0; }

  bf16x8 fa[4], fb[4];
  f32x4 axa[3], axb[3];
  {
    bf16x8 f0[4];
#pragma unroll
    for (int k0 = 0; k0 < 4; k0++) {
      f0[k0] = ldg8(&xb[xrow + 0 * 128 + k0 * 32]);
      fa[k0] = ldg8(&xb[xrow + 1 * 128 + k0 * 32]);
    }
#pragma unroll
    for (int g = 0; g < 3; g++) axa[g] = (f32x4){0.f, 0.f, 0.f, 0.f};
#pragma unroll
    for (int k0 = 0; k0 < 4; k0++)
#pragma unroll
      for (int g = 0; g < 3; g++)
        axa[g] = __builtin_amdgcn_mfma_f32_16x16x32_bf16(f0[k0], wfx[g][k0], axa[g], 0, 0, 0);
  }
  scan_barrier();

  auto step = [&](int t, bf16x8 (&fcur)[4], bf16x8 (&fnext)[4],
                  f32x4 (&axc)[3], f32x4 (&axn)[3], const u16* hrd, u16* hwr) {
#pragma unroll
    for (int k0 = 0; k0 < 4; k0++)
      fnext[k0] = ldg8(&xb[xrow + (u32)(t + 2) * 128 + k0 * 32]);
    bf16x8 af[4];
#pragma unroll
    for (int k0 = 0; k0 < 4; k0++) af[k0] = ldg8(&hrd[hbase + k0 * 32]);
    f32x4 ah[3];
#pragma unroll
    for (int g = 0; g < 3; g++) ah[g] = (f32x4){0.f, 0.f, 0.f, 0.f};
#pragma unroll
    for (int k0 = 0; k0 < 4; k0++)
#pragma unroll
      for (int g = 0; g < 3; g++)
        ah[g] = __builtin_amdgcn_mfma_f32_16x16x32_bf16(af[k0], wfh[g][k0], ah[g], 0, 0, 0);
#pragma unroll
    for (int g = 0; g < 3; g++) axn[g] = (f32x4){0.f, 0.f, 0.f, 0.f};
#pragma unroll
    for (int k0 = 0; k0 < 4; k0++)
#pragma unroll
      for (int g = 0; g < 3; g++)
        axn[g] = __builtin_amdgcn_mfma_f32_16x16x32_bf16(fcur[k0], wfx[g][k0], axn[g], 0, 0, 0);
    float rr = sigm(axc[0][0] + ah[0][0] + brz);
    float zz = sigm(axc[1][0] + ah[1][0] + bzz);
    float nn = tanh_f(axc[2][0] + bnx + rr * (ah[2][0] + bnh));
    hp = nn + zz * (hp - nn);
    hwr[mrow * HSTR + col] = f2bf(hp);
    scan_barrier();
  };

#pragma unroll 1
  for (int t2 = 0; t2 < TT; t2 += 2) {
    step(t2, fa, fb, axa, axb, hb0, hb1);
    step(t2 + 1, fb, fa, axb, axa, hb1, hb0);
  }
  hlast[(size_t)(b0 + q) * 128 + col] = hp;
}

// ---------------------------------------------------------------------------
// Head: LN(gru) -> relu -> fc1 -> LN(fc1) -> relu -> fco. One block per row.
// ---------------------------------------------------------------------------
__global__ __launch_bounds__(256) void head(
    const float* __restrict__ hlast,
    const float* __restrict__ g1, const float* __restrict__ b1,
    const float* __restrict__ fc1Wt, const float* __restrict__ fc1b,
    const float* __restrict__ g2, const float* __restrict__ b2,
    const float* __restrict__ fcoWt, const float* __restrict__ fcob,
    float* __restrict__ out) {
  const int b = blockIdx.x, tid = threadIdx.x;
  __shared__ float yv[128];
  __shared__ float zv[160];
  __shared__ float red[8];
  float v = (tid < 128) ? hlast[b * 128 + tid] : 0.f;
  float p1 = v, p2 = v * v;
#pragma unroll
  for (int m = 1; m < 64; m <<= 1) { p1 += __shfl_xor(p1, m); p2 += __shfl_xor(p2, m); }
  if ((tid & 63) == 0) { red[(tid >> 6) * 2] = p1; red[(tid >> 6) * 2 + 1] = p2; }
  __syncthreads();
  float s1 = red[0] + red[2] + red[4] + red[6];
  float s2 = red[1] + red[3] + red[5] + red[7];
  float mean = s1 * (1.f / 128.f);
  float var = s2 * (1.f / 128.f) - mean * mean;
  float rs = rsqrtf(var + 1e-5f);
  if (tid < 128) yv[tid] = fmaxf((v - mean) * rs * g1[tid] + b1[tid], 0.f);
  __syncthreads();
  float z = 0.f;
  if (tid < 160) {
    z = fc1b[tid];
    for (int g = 0; g < 128; g++) z += yv[g] * fc1Wt[g * 160 + tid];
  }
  float q1 = (tid < 160) ? z : 0.f;
  float q2 = (tid < 160) ? z * z : 0.f;
#pragma unroll
  for (int m = 1; m < 64; m <<= 1) { q1 += __shfl_xor(q1, m); q2 += __shfl_xor(q2, m); }
  __syncthreads();
  if ((tid & 63) == 0) { red[(tid >> 6) * 2] = q1; red[(tid >> 6) * 2 + 1] = q2; }
  __syncthreads();
  s1 = red[0] + red[2] + red[4] + red[6];
  s2 = red[1] + red[3] + red[5] + red[7];
  mean = s1 * (1.f / 160.f);
  var = s2 * (1.f / 160.f) - mean * mean;
  rs = rsqrtf(var + 1e-5f);
  if (tid < 160) zv[tid] = fmaxf((z - mean) * rs * g2[tid] + b2[tid], 0.f);
  __syncthreads();
  if (tid < 64) {
    float o = fcob[tid];
    for (int f = 0; f < 160; f++) o += zv[f] * fcoWt[f * 64 + tid];
    out[b * 64 + tid] = o;
  }
}

// ---------------------------------------------------------------------------
// workspace layout (bytes). xbf then lout first: small OOB prefetch reads
// (t+2 past end) land in the adjacent region harmlessly.
// ---------------------------------------------------------------------------
static constexpr size_t OFF_XBF   = 0;                          // 67,108,864
static constexpr size_t OFF_LOUT  = 67108864;                   // 67,108,864
static constexpr size_t OFF_WIHL  = OFF_LOUT + 67108864;        // 131,072
static constexpr size_t OFF_WHHL  = OFF_WIHL + 131072;          // 131,072
static constexpr size_t OFF_WIHG  = OFF_WHHL + 131072;          // 98,304
static constexpr size_t OFF_WHHG  = OFF_WIHG + 98304;           // 98,304
static constexpr size_t OFF_BIASL = OFF_WHHG + 98304;           // 2,048
static constexpr size_t OFF_FC1T  = OFF_BIASL + 2048;           // 81,920
static constexpr size_t OFF_FCOT  = OFF_FC1T + 81920;           // 40,960
static constexpr size_t OFF_HLAST = OFF_FCOT + 40960;           // 262,144

extern "C" void kernel_launch(void* const* d_in, const int* in_sizes, int n_in,
                              void* d_out, int out_size, void* d_ws, size_t ws_size,
                              hipStream_t stream) {
  (void)in_sizes; (void)n_in; (void)out_size; (void)ws_size;
  const float* x    = (const float*)d_in[0];
  const float* lWih = (const float*)d_in[1];
  const float* lWhh = (const float*)d_in[2];
  const float* lbih = (const float*)d_in[3];
  const float* lbhh = (const float*)d_in[4];
  const float* gWih = (const float*)d_in[5];
  const float* gWhh = (const float*)d_in[6];
  const float* gbih = (const float*)d_in[7];
  const float* gbhh = (const float*)d_in[8];
  const float* lnLg = (const float*)d_in[9];
  const float* lnLb = (const float*)d_in[10];
  const float* lnGg = (const float*)d_in[11];
  const float* lnGb = (const float*)d_in[12];
  const float* fc1W = (const float*)d_in[13];
  const float* fc1b = (const float*)d_in[14];
  const float* lnFg = (const float*)d_in[15];
  const float* lnFb = (const float*)d_in[16];
  const float* fcoW = (const float*)d_in[17];
  const float* fcob = (const float*)d_in[18];

  char* ws = (char*)d_ws;
  u16* xbf    = (u16*)(ws + OFF_XBF);
  u16* lout   = (u16*)(ws + OFF_LOUT);
  u16* wihlb  = (u16*)(ws + OFF_WIHL);
  u16* whhlb  = (u16*)(ws + OFF_WHHL);
  u16* wihgb  = (u16*)(ws + OFF_WIHG);
  u16* whhgb  = (u16*)(ws + OFF_WHHG);
  float* biasl = (float*)(ws + OFF_BIASL);
  float* fc1Wt = (float*)(ws + OFF_FC1T);
  float* fcoWt = (float*)(ws + OFF_FCOT);
  float* hlast = (float*)(ws + OFF_HLAST);
  float* out   = (float*)d_out;

  prep_x<<<32768, 256, 0, stream>>>(x, xbf);
  prep_misc<<<1024, 256, 0, stream>>>(lWih, lWhh, gWih, gWhh, lbih, lbhh, fc1W, fcoW,
                                      wihlb, whhlb, wihgb, whhgb, biasl, fc1Wt, fcoWt);
  lstm_scan<<<128, 512, 0, stream>>>(xbf, whhlb, wihlb, biasl, lout);
  ln_pass<<<65536, 256, 0, stream>>>(lout, lnLg, lnLb);
  gru_scan<<<128, 512, 0, stream>>>(lout, whhgb, wihgb, gbih, gbhh, hlast);
  head<<<512, 256, 0, stream>>>(hlast, lnGg, lnGb, fc1Wt, fc1b, lnFg, lnFb, fcoWt, fcob, out);
}